// Round 1
// baseline (78.143 us; speedup 1.0000x reference)
//
#include <hip/hip_runtime.h>
#include <math.h>

// Batched FK chain: re = T1..T25; out = concat(points = re[:3,3], vectors = re[:3,2]).
// Constant matrices are signed permutes + translations; propagate p (w=1) and
// v (w=0) right-to-left.
//
// This revision: 512 items per 256-thread block (2 items/thread), disjoint LDS
// in/out staging regions so the barrier count drops from 3 per 256 items to
// 2 per 512 items, and block count halves (4096 -> 2048). All global I/O stays
// fully float4-coalesced:
//   in:  512*7 floats = 896 float4 per block
//   out: 2 x 512*3 floats = 2 x 384 float4 per block
// LDS readback strides (14, 6) give <=4-way bank aliasing (~1.6x on cheap LDS
// ops, negligible). LDS total = 14336 + 12288 = 26.6 KB -> ~6 blocks/CU.

#define DEGf 0.017453292519943295f

__device__ __forceinline__ void rotz(float& x, float& y, float c, float s) {
    float nx = c * x - s * y;
    float ny = s * x + c * y;
    x = nx; y = ny;
}

__device__ __forceinline__ void fk_chain(const float th[7],
                                         float& px, float& py, float& pz,
                                         float& vx, float& vy, float& vz) {
    // Angles in radians (signs/scales folded from the reference chain)
    const float a0 = th[0] * DEGf;
    const float a1 = th[1] * DEGf;
    const float a2 = -th[2] * DEGf;
    const float a3 = -th[3] * DEGf;
    const float a4 = th[4] * (-0.5f * DEGf);
    const float a5 = (th[5] * (1.0f / 4.5f) + 10.0f) * DEGf;
    const float a6 = (20.0f + (th[6] + 180.0f) * (1.0f / 4.5f)) * DEGf;

    float s0, c0, s1, c1, s2, c2, s3, c3, s4v, c4, s5, c5, s6, c6;
    __sincosf(a0, &s0, &c0);
    __sincosf(a1, &s1, &c1);
    __sincosf(a2, &s2, &c2);
    __sincosf(a3, &s3, &c3);
    __sincosf(a4, &s4v, &c4);
    __sincosf(a5, &s5, &c5);
    __sincosf(a6, &s6, &c6);

    // After T25=Ry(90): p = col3 = (0,0,0); v = col2 = (1,0,0).
    px = 6.0f; py = 0.0f; pz = 0.0f;                 // T24: Txyz(6,0,0)
    vx = 1.0f; vy = 0.0f; vz = 0.0f;
    float t;

    rotz(px, py, c6, s6); rotz(vx, vy, c6, s6);      // T23 = Rz(a6)
    px += 6.0f; py -= 1.0f;                          // T22, T21
    rotz(px, py, c5, s5); rotz(vx, vy, c5, s5);      // T20 = Rz(a5)
    t = px; px = py; py = -t;                        // T19 = Rz(-90)
    t = vx; vx = vy; vy = -t;
    t = py; py = pz; pz = -t;                        // T18 = Rx(-90)
    t = vy; vy = vz; vz = -t;
    pz += 10.0f;                                     // T17
    rotz(px, py, c4, s4v); rotz(vx, vy, c4, s4v);    // T16 = Rz(a4)
    t = px; px = pz; pz = -t;                        // T15 = Ry(90)
    t = vx; vx = vz; vz = -t;
    px += 10.0f;                                     // T14
    rotz(px, py, c3, s3); rotz(vx, vy, c3, s3);      // T13 = Rz(a3)
    px = -px; py = -py; vx = -vx; vy = -vy;          // T12 = Rz(180)
    t = py; py = -pz; pz = t;                        // T11 = Rx(90)
    t = vy; vy = -vz; vz = t;
    px += 17.5f;                                     // T10
    rotz(px, py, c2, s2); rotz(vx, vy, c2, s2);      // T9 = Rz(a2)
    t = py; py = pz; pz = -t;                        // T8 = Rx(-90)
    t = vy; vy = vz; vz = -t;
    px += 3.0f; pz += 9.5f;                          // T7
    rotz(px, py, c1, s1); rotz(vx, vy, c1, s1);      // T6 = Rz(a1)
    t = px; px = pz; pz = -t;                        // T5 = Ry(90)
    t = vx; vx = vz; vz = -t;
    py -= 1.5f; pz += 2.5f;                          // T4
    rotz(px, py, c0, s0); rotz(vx, vy, c0, s0);      // T3 = Rz(a0)
    t = px; px = -py; py = t;                        // T2 = Rz(90)
    t = vx; vx = -vy; vy = t;
    py += 5.0f; pz += 19.5f;                         // T1
}

__global__ __launch_bounds__(256) void fk_kernel(const float* __restrict__ thetas,
                                                 float* __restrict__ out,
                                                 int B) {
    __shared__ float sIn[7 * 512];    // 14336 B: staged thetas
    __shared__ float sOut[6 * 512];   // 12288 B: [points 1536 | vectors 1536]
    const int tid = threadIdx.x;
    const long long blockBase = (long long)blockIdx.x * 512;
    const bool full = (blockBase + 512 <= (long long)B) && ((B & 3) == 0);

    if (full) {
        // --- stage in: 896 float4 = 3584 floats per block, fully coalesced ---
        const float4* t4 = (const float4*)(thetas + blockBase * 7);
        float4* si4 = (float4*)sIn;
        si4[tid]       = t4[tid];
        si4[256 + tid] = t4[256 + tid];
        si4[512 + tid] = t4[512 + tid];
        if (tid < 128) si4[768 + tid] = t4[768 + tid];
        __syncthreads();

        // --- compute 2 items/thread; write results to disjoint out-stage ---
#pragma unroll
        for (int m = 0; m < 2; ++m) {
            const int it = tid * 2 + m;           // 0..511
            float th[7];
#pragma unroll
            for (int j = 0; j < 7; ++j) th[j] = sIn[it * 7 + j];
            float px, py, pz, vx, vy, vz;
            fk_chain(th, px, py, pz, vx, vy, vz);
            sOut[it * 3 + 0] = px;
            sOut[it * 3 + 1] = py;
            sOut[it * 3 + 2] = pz;
            sOut[1536 + it * 3 + 0] = vx;
            sOut[1536 + it * 3 + 1] = vy;
            sOut[1536 + it * 3 + 2] = vz;
        }
        __syncthreads();

        // --- store: 2 x 384 float4 per block, fully coalesced ---
        const float4* so4 = (const float4*)sOut;
        float4* o4p = (float4*)(out + blockBase * 3);
        float4* o4v = (float4*)(out + (long long)B * 3 + blockBase * 3);
        o4p[tid] = so4[tid];
        if (tid < 128) o4p[256 + tid] = so4[256 + tid];
        o4v[tid] = so4[384 + tid];
        if (tid < 128) o4v[256 + tid] = so4[384 + 256 + tid];
    } else {
        // Tail / unaligned fallback: scalar per-item path
#pragma unroll
        for (int m = 0; m < 2; ++m) {
            const long long i = blockBase + tid * 2 + m;
            if (i >= (long long)B) continue;
            float th[7];
#pragma unroll
            for (int j = 0; j < 7; ++j) th[j] = thetas[i * 7 + j];
            float px, py, pz, vx, vy, vz;
            fk_chain(th, px, py, pz, vx, vy, vz);
            float* po = out + 3ll * i;
            po[0] = px; po[1] = py; po[2] = pz;
            float* vo = out + 3ll * (long long)B + 3ll * i;
            vo[0] = vx; vo[1] = vy; vo[2] = vz;
        }
    }
}

extern "C" void kernel_launch(void* const* d_in, const int* in_sizes, int n_in,
                              void* d_out, int out_size, void* d_ws, size_t ws_size,
                              hipStream_t stream) {
    const float* thetas = (const float*)d_in[0];
    float* out = (float*)d_out;
    const int B = in_sizes[0] / 7;
    const int block = 256;
    const int grid = (int)(((long long)B + 511) / 512);
    fk_kernel<<<grid, block, 0, stream>>>(thetas, out, B);
}